// Round 8
// baseline (1158.306 us; speedup 1.0000x reference)
//
#include <hip/hip_runtime.h>
#include <math.h>

#define BS 32
#define NI 196
#define NT 256
#define DD 1024

typedef unsigned int u32;
typedef __attribute__((ext_vector_type(8))) short bf16x8;
typedef __attribute__((ext_vector_type(4))) float f32x4;

__device__ __forceinline__ u32 fenc(float f){ u32 u = __float_as_uint(f); return (u & 0x80000000u) ? ~u : (u | 0x80000000u); }
__device__ __forceinline__ float fdec(u32 u){ return __uint_as_float((u & 0x80000000u) ? (u & 0x7fffffffu) : ~u); }

// bf16 helpers (manual RNE)
__device__ __forceinline__ unsigned short f2bf(float f){
  u32 u = __float_as_uint(f);
  u32 r = (u + 0x7FFFu + ((u >> 16) & 1u)) >> 16;
  return (unsigned short)r;
}
__device__ __forceinline__ float bf2f(unsigned short h){ return __uint_as_float((u32)h << 16); }

template<int CTRL>
__device__ __forceinline__ float dppadd(float x){
  int y = __builtin_amdgcn_update_dpp(0, __float_as_int(x), CTRL, 0xF, 0xF, false);
  return x + __int_as_float(y);
}
// sum over each 32-lane half of the wave
__device__ __forceinline__ float rowsum32(float x){
  x = dppadd<0xB1>(x);    // quad_perm xor1
  x = dppadd<0x4E>(x);    // quad_perm xor2
  x = dppadd<0x141>(x);   // row_half_mirror (pairs within 8)
  x = dppadd<0x128>(x);   // row_ror:8 (pairs within 16)
  x += __shfl_xor(x, 16);
  return x;
}

// ---------------- init ----------------
__global__ void init_mm_k(u32* mm){
  int t = threadIdx.x;
  if (t < 3){ mm[2*t] = 0xFFFFFFFFu; mm[2*t+1] = 0u; }
}

// ---------------- prep: normalize rows, split to bf16 hi/lo ----------------
__global__ __launch_bounds__(256) void prep_k(const float* __restrict__ feat,
                                              const float* __restrict__ mask,
                                              unsigned short* __restrict__ hi,
                                              unsigned short* __restrict__ lo, int R){
  int b = blockIdx.y, r = blockIdx.x, t = threadIdx.x;
  size_t rowoff = ((size_t)b*R + r)*DD;
  float4 v = ((const float4*)(feat + rowoff))[t];
  float s = v.x*v.x + v.y*v.y + v.z*v.z + v.w*v.w;
  #pragma unroll
  for (int m = 32; m >= 1; m >>= 1) s += __shfl_xor(s, m);
  __shared__ float ps[4];
  if ((t & 63) == 0) ps[t >> 6] = s;
  __syncthreads();
  float tot = ps[0] + ps[1] + ps[2] + ps[3];
  float mv = mask ? mask[b*R + r] : 1.0f;
  float sc = mv / (mv * sqrtf(tot) + 1e-12f);
  float x[4] = {v.x*sc, v.y*sc, v.z*sc, v.w*sc};
  unsigned short h[4], l[4];
  #pragma unroll
  for (int i = 0; i < 4; ++i){
    h[i] = f2bf(x[i]);
    l[i] = f2bf(x[i] - bf2f(h[i]));
  }
  *(ushort4*)(hi + rowoff + t*4) = make_ushort4(h[0],h[1],h[2],h[3]);
  *(ushort4*)(lo + rowoff + t*4) = make_ushort4(l[0],l[1],l[2],l[3]);
}

// ---------------- MFMA cos GEMM: C = 1 - Xn . Yn^T (128x128 tile) ----------------
__global__ __launch_bounds__(256) void cosmm_k(const unsigned short* __restrict__ Xh,
                                               const unsigned short* __restrict__ Xl,
                                               const unsigned short* __restrict__ Yh,
                                               const unsigned short* __restrict__ Yl,
                                               float* __restrict__ C, int M, int N, int nTN){
  __shared__ unsigned short Ah[128*40], Al[128*40], Bh[128*40], Bl[128*40];
  int b = blockIdx.y;
  int tm = (blockIdx.x / nTN) * 128, tn = (blockIdx.x % nTN) * 128;
  int t = threadIdx.x, lane = t & 63, w = t >> 6;
  int wm = (w >> 1) * 64, wn = (w & 1) * 64;
  const unsigned short* Xhb = Xh + (size_t)b*M*DD;
  const unsigned short* Xlb = Xl + (size_t)b*M*DD;
  const unsigned short* Yhb = Yh + (size_t)b*N*DD;
  const unsigned short* Ylb = Yl + (size_t)b*N*DD;
  f32x4 acc[4][4];
  #pragma unroll
  for (int m = 0; m < 4; ++m)
    #pragma unroll
    for (int n = 0; n < 4; ++n) acc[m][n] = (f32x4){0.f,0.f,0.f,0.f};

  int sr0 = t >> 2, sc0 = (t & 3) * 8;
  int gr0 = min(tm + sr0, M-1),      gr1 = min(tm + sr0 + 64, M-1);
  int gc0 = min(tn + sr0, N-1),      gc1 = min(tn + sr0 + 64, N-1);
  const unsigned short* pa0 = Xhb + (size_t)gr0*DD + sc0;
  const unsigned short* pa1 = Xhb + (size_t)gr1*DD + sc0;
  const unsigned short* pa2 = Xlb + (size_t)gr0*DD + sc0;
  const unsigned short* pa3 = Xlb + (size_t)gr1*DD + sc0;
  const unsigned short* pb0 = Yhb + (size_t)gc0*DD + sc0;
  const unsigned short* pb1 = Yhb + (size_t)gc1*DD + sc0;
  const unsigned short* pb2 = Ylb + (size_t)gc0*DD + sc0;
  const unsigned short* pb3 = Ylb + (size_t)gc1*DD + sc0;
  int fr = lane & 15, fk = (lane >> 4) * 8;

  for (int k0 = 0; k0 < DD; k0 += 32){
    float4 a0 = *(const float4*)(pa0 + k0);
    float4 a1 = *(const float4*)(pa1 + k0);
    float4 a2 = *(const float4*)(pa2 + k0);
    float4 a3 = *(const float4*)(pa3 + k0);
    float4 b0 = *(const float4*)(pb0 + k0);
    float4 b1 = *(const float4*)(pb1 + k0);
    float4 b2 = *(const float4*)(pb2 + k0);
    float4 b3 = *(const float4*)(pb3 + k0);
    __syncthreads();
    *(float4*)&Ah[sr0*40 + sc0]      = a0;
    *(float4*)&Ah[(sr0+64)*40 + sc0] = a1;
    *(float4*)&Al[sr0*40 + sc0]      = a2;
    *(float4*)&Al[(sr0+64)*40 + sc0] = a3;
    *(float4*)&Bh[sr0*40 + sc0]      = b0;
    *(float4*)&Bh[(sr0+64)*40 + sc0] = b1;
    *(float4*)&Bl[sr0*40 + sc0]      = b2;
    *(float4*)&Bl[(sr0+64)*40 + sc0] = b3;
    __syncthreads();
    bf16x8 ah[4], al[4], bh[4], bl[4];
    #pragma unroll
    for (int m = 0; m < 4; ++m){
      int r = wm + m*16 + fr;
      ah[m] = *(bf16x8*)&Ah[r*40 + fk];
      al[m] = *(bf16x8*)&Al[r*40 + fk];
    }
    #pragma unroll
    for (int n = 0; n < 4; ++n){
      int r = wn + n*16 + fr;
      bh[n] = *(bf16x8*)&Bh[r*40 + fk];
      bl[n] = *(bf16x8*)&Bl[r*40 + fk];
    }
    #pragma unroll
    for (int m = 0; m < 4; ++m)
      #pragma unroll
      for (int n = 0; n < 4; ++n){
        acc[m][n] = __builtin_amdgcn_mfma_f32_16x16x32_bf16(ah[m], bh[n], acc[m][n], 0,0,0);
        acc[m][n] = __builtin_amdgcn_mfma_f32_16x16x32_bf16(ah[m], bl[n], acc[m][n], 0,0,0);
        acc[m][n] = __builtin_amdgcn_mfma_f32_16x16x32_bf16(al[m], bh[n], acc[m][n], 0,0,0);
      }
  }
  float* Cb = C + (size_t)b*M*N;
  #pragma unroll
  for (int m = 0; m < 4; ++m){
    int row0 = tm + wm + m*16 + ((lane >> 4) << 2);
    #pragma unroll
    for (int n = 0; n < 4; ++n){
      int col = tn + wn + n*16 + (lane & 15);
      if (col < N){
        #pragma unroll
        for (int r = 0; r < 4; ++r){
          int row = row0 + r;
          if (row < M) Cb[(size_t)row*N + col] = 1.0f - acc[m][n][r];
        }
      }
    }
  }
}

// ---------------- MFMA NT GEMM on pre-split bf16 operands (64x64 tile) ----------------
template<int EPI>
__global__ __launch_bounds__(256) void mmnt_k(const unsigned short* __restrict__ Ah,
                                              const unsigned short* __restrict__ Al,
                                              const unsigned short* __restrict__ Bh,
                                              const unsigned short* __restrict__ Bl,
                                              float* __restrict__ C,
                                              int M, int N, int Kp, int nTN,
                                              const float* __restrict__ av,
                                              const float* __restrict__ bv){
  __shared__ unsigned short As_h[64*40], As_l[64*40], Bs_h[64*40], Bs_l[64*40];
  int b = blockIdx.y;
  int tm = (blockIdx.x / nTN) * 64, tn = (blockIdx.x % nTN) * 64;
  int t = threadIdx.x, lane = t & 63, w = t >> 6;
  int wm = (w >> 1) * 32, wn = (w & 1) * 32;
  const unsigned short* Ahb = Ah + (size_t)b*M*Kp;
  const unsigned short* Alb = Al + (size_t)b*M*Kp;
  const unsigned short* Bhb = Bh + (size_t)b*N*Kp;
  const unsigned short* Blb = Bl + (size_t)b*N*Kp;
  f32x4 acc[2][2];
  #pragma unroll
  for (int m = 0; m < 2; ++m)
    #pragma unroll
    for (int n = 0; n < 2; ++n) acc[m][n] = (f32x4){0.f,0.f,0.f,0.f};

  int srow = t >> 2, sch = (t & 3) * 8;
  int ga = min(tm + srow, M-1), gbn = min(tn + srow, N-1);
  const unsigned short* pah = Ahb + (size_t)ga*Kp + sch;
  const unsigned short* pal = Alb + (size_t)ga*Kp + sch;
  const unsigned short* pbh = Bhb + (size_t)gbn*Kp + sch;
  const unsigned short* pbl = Blb + (size_t)gbn*Kp + sch;
  int fr = lane & 15, fk = (lane >> 4) * 8;

  for (int k0 = 0; k0 < Kp; k0 += 32){
    float4 vah = *(const float4*)(pah + k0);
    float4 val = *(const float4*)(pal + k0);
    float4 vbh = *(const float4*)(pbh + k0);
    float4 vbl = *(const float4*)(pbl + k0);
    __syncthreads();
    *(float4*)&As_h[srow*40 + sch] = vah;
    *(float4*)&As_l[srow*40 + sch] = val;
    *(float4*)&Bs_h[srow*40 + sch] = vbh;
    *(float4*)&Bs_l[srow*40 + sch] = vbl;
    __syncthreads();
    bf16x8 fah[2], fal[2], fbh[2], fbl[2];
    #pragma unroll
    for (int m = 0; m < 2; ++m){
      int r = wm + m*16 + fr;
      fah[m] = *(bf16x8*)&As_h[r*40 + fk];
      fal[m] = *(bf16x8*)&As_l[r*40 + fk];
    }
    #pragma unroll
    for (int n = 0; n < 2; ++n){
      int r = wn + n*16 + fr;
      fbh[n] = *(bf16x8*)&Bs_h[r*40 + fk];
      fbl[n] = *(bf16x8*)&Bs_l[r*40 + fk];
    }
    #pragma unroll
    for (int m = 0; m < 2; ++m)
      #pragma unroll
      for (int n = 0; n < 2; ++n){
        acc[m][n] = __builtin_amdgcn_mfma_f32_16x16x32_bf16(fah[m], fbh[n], acc[m][n], 0,0,0);
        acc[m][n] = __builtin_amdgcn_mfma_f32_16x16x32_bf16(fah[m], fbl[n], acc[m][n], 0,0,0);
        acc[m][n] = __builtin_amdgcn_mfma_f32_16x16x32_bf16(fal[m], fbh[n], acc[m][n], 0,0,0);
      }
  }
  float* Cb = C + (size_t)b*M*N;
  #pragma unroll
  for (int m = 0; m < 2; ++m){
    int row0 = tm + wm + m*16 + ((lane >> 4) << 2);
    #pragma unroll
    for (int n = 0; n < 2; ++n){
      int col = tn + wn + n*16 + (lane & 15);
      #pragma unroll
      for (int r = 0; r < 4; ++r){
        int row = row0 + r;
        if (row < M){
          float x = acc[m][n][r];
          if (EPI == 2) x = av[b*M + row] + bv[b*N + col] - 2.0f*x;
          Cb[(size_t)row*N + col] = x;
        }
      }
    }
  }
}

// ---------------- plain bf16 hi/lo split with K zero-padding ----------------
__global__ __launch_bounds__(256) void split_k(const float* __restrict__ src,
                                               unsigned short* __restrict__ dsth,
                                               unsigned short* __restrict__ dstl,
                                               int Cin, int Kp){
  int r = blockIdx.x, b = blockIdx.y, j = threadIdx.x, R = gridDim.x;
  if (j >= Kp) return;
  float v = (j < Cin) ? src[((size_t)b*R + r)*Cin + j] : 0.f;
  unsigned short h = f2bf(v);
  unsigned short l = f2bf(v - bf2f(h));
  size_t o = ((size_t)b*R + r)*Kp + j;
  dsth[o] = h; dstl[o] = l;
}

// ---------------- transpose + split: gamma [196][256] -> gT h/l [256][224] ----------------
__global__ __launch_bounds__(256) void splitT_k(const float* __restrict__ g,
                                                unsigned short* __restrict__ th,
                                                unsigned short* __restrict__ tl){
  __shared__ float tile[32][33];
  int j0 = blockIdx.x * 32, k0 = blockIdx.y * 32, b = blockIdx.z;
  int t = threadIdx.x;
  const float* gb = g + (size_t)b*NI*NT;
  {
    int a = t >> 3, ch = t & 7;
    int k = k0 + a;
    float4 v = make_float4(0.f,0.f,0.f,0.f);
    if (k < NI) v = *(const float4*)(gb + (size_t)k*NT + j0 + ch*4);
    tile[a][ch*4+0] = v.x; tile[a][ch*4+1] = v.y; tile[a][ch*4+2] = v.z; tile[a][ch*4+3] = v.w;
  }
  __syncthreads();
  {
    int jloc = t >> 3, ch = t & 7;
    int j = j0 + jloc;
    unsigned short h[4], l[4];
    #pragma unroll
    for (int r = 0; r < 4; ++r){
      float v = tile[ch*4 + r][jloc];
      h[r] = f2bf(v);
      l[r] = f2bf(v - bf2f(h[r]));
    }
    size_t o = ((size_t)b*NT + j)*224 + k0 + ch*4;
    *(ushort4*)(th + o) = make_ushort4(h[0],h[1],h[2],h[3]);
    *(ushort4*)(tl + o) = make_ushort4(l[0],l[1],l[2],l[3]);
  }
}

// ---------------- global min/max ----------------
__global__ __launch_bounds__(256) void minmax_k(const float* __restrict__ X, size_t cnt, u32* __restrict__ mm){
  size_t stride = (size_t)gridDim.x * blockDim.x;
  float mn = 3.402823466e38f, mx = -3.402823466e38f;
  for (size_t i = (size_t)blockIdx.x*blockDim.x + threadIdx.x; i < cnt; i += stride){
    float v = X[i]; mn = fminf(mn, v); mx = fmaxf(mx, v);
  }
  #pragma unroll
  for (int m = 32; m >= 1; m >>= 1){ mn = fminf(mn, __shfl_xor(mn, m)); mx = fmaxf(mx, __shfl_xor(mx, m)); }
  __shared__ float smn[4], smx[4];
  int t = threadIdx.x;
  if ((t & 63) == 0){ smn[t>>6] = mn; smx[t>>6] = mx; }
  __syncthreads();
  if (t == 0){
    mn = fminf(fminf(smn[0], smn[1]), fminf(smn[2], smn[3]));
    mx = fmaxf(fmaxf(smx[0], smx[1]), fmaxf(smx[2], smx[3]));
    atomicMin(&mm[0], fenc(mn));
    atomicMax(&mm[1], fenc(mx));
  }
}

// ---------------- threshold-relu (+ optional {0,1}->{1e-5,1} mask) ----------------
__global__ __launch_bounds__(256) void thresh_k(float* __restrict__ X, const int* __restrict__ msk,
                                                size_t cnt, const u32* __restrict__ mm){
  float mn = fdec(mm[0]), mx = fdec(mm[1]);
  float thr = mn + 0.1f * (mx - mn);
  size_t stride = (size_t)gridDim.x * blockDim.x;
  for (size_t i = (size_t)blockIdx.x*blockDim.x + threadIdx.x; i < cnt; i += stride){
    float v = X[i] - thr;
    v = v > 0.f ? v : 0.f;
    if (msk) v *= (msk[i] == 1 ? 1.0f : 1e-5f);
    X[i] = v;
  }
}

// ---------------- row mean of squares ----------------
__global__ __launch_bounds__(64) void rowmeansq_k(const float* __restrict__ X, float* __restrict__ out, int R, int Cc){
  int b = blockIdx.y, r = blockIdx.x, t = threadIdx.x;
  const float* row = X + ((size_t)b*R + r) * Cc;
  float s = 0.f;
  for (int j = t; j < Cc; j += 64){ float v = row[j]; s = fmaf(v, v, s); }
  #pragma unroll
  for (int m = 32; m >= 1; m >>= 1) s += __shfl_xor(s, m);
  if (t == 0) out[b*R + r] = s / (float)Cc;
}

// ---------------- fill ----------------
__global__ void fill_k(float* __restrict__ X, size_t cnt, float val){
  size_t stride = (size_t)gridDim.x * blockDim.x;
  for (size_t i = (size_t)blockIdx.x*blockDim.x + threadIdx.x; i < cnt; i += stride) X[i] = val;
}

// ---------------- IPOT v4: T fp32 in regs, P bf16-packed in LDS ----------------
// One block (256 thr = 4 waves) per batch, 1 block/CU.
// thread: c = t&31 (cols j = c+32l, l<8), R = t>>5 in 0..7 (rows i = R+8k, k<25;
// k==24 valid iff R<4 -> 196 rows).
// State: T[25][8] fp32 = 200 VGPR + ~40 working = ~240 <= 256 arch cap -> NO spill
// of any kind (the r5/r6 lesson: >256 arch regs => compiler scratch-spills).
// P = exp(-2C) stored ONCE as single-bf16 (2 packed/u32) in LDS (100 KB, private
// per-thread slots, no barriers for it). bf16 P is a fixed per-element (1+eps),
// eps<=2^-9 perturbation of the kernel -> T deviates <=(1+eps)^20 ~ 4% worst on
// entries <=5e-3 -> <=2e-4 < 6.35e-4 threshold; marginals re-enforced exactly.
// wd re-reads exact fp32 C from global (L2-warm).
template<bool WD>
__global__ __launch_bounds__(256, 1) void ipotr3_k(const float* __restrict__ Cmat,
                                                   float* __restrict__ Tout,
                                                   float* __restrict__ distBuf){
  __shared__ u32 Ppk[8*25*32*4];      // [R][k][c][l2] pairs -> 102,400 B
  __shared__ float cp[8][NT];         // 8 KB col-partial reduce
  __shared__ float sgm[NT];
  __shared__ float wp[4];
  const u32 HIM = 0xFFFF0000u;
  int b = blockIdx.x, t = threadIdx.x;
  int c = t & 31, R = t >> 5;
  const float* Cb = Cmat + (size_t)b * NI * NT;
  bool ok24 = (R < 4);                 // row 192+R valid iff R<4
  u32* myP = &Ppk[((R*25)*32 + c)*4];

  float T[25][8];
  // ---- load C -> P=exp(-2C) -> pack bf16 pairs to LDS ----
  #pragma unroll
  for (int k = 0; k < 25; ++k){
    int i = R + 8*k;
    bool ok = (k < 24) | ok24;
    float cv[8];
    #pragma unroll
    for (int l = 0; l < 8; ++l)
      cv[l] = ok ? Cb[(size_t)i*NT + c + 32*l] : 0.f;
    u32 pk[4];
    #pragma unroll
    for (int j = 0; j < 4; ++j){
      float p0 = ok ? __expf(-2.0f*cv[2*j])   : 0.f;
      float p1 = ok ? __expf(-2.0f*cv[2*j+1]) : 0.f;
      pk[j] = (u32)f2bf(p0) | ((u32)f2bf(p1) << 16);
    }
    *(uint4*)(myP + k*128) = make_uint4(pk[0], pk[1], pk[2], pk[3]);
    #pragma unroll
    for (int l = 0; l < 8; ++l) T[k][l] = ok ? 1.f : 0.f;
  }

  float sl[8];
  #pragma unroll
  for (int l = 0; l < 8; ++l) sl[l] = 1.0f / (float)NT;   // sigma carry (init 1/m)

  #pragma unroll 1
  for (int it = 0; it < 20; ++it){
    float cpl[8];
    #pragma unroll
    for (int l = 0; l < 8; ++l) cpl[l] = 0.f;
    #pragma unroll
    for (int k = 0; k < 25; ++k){
      uint4 pq = *(const uint4*)(myP + k*128);
      u32 ps[4] = {pq.x, pq.y, pq.z, pq.w};
      float a = 0.f;
      #pragma unroll
      for (int j = 0; j < 4; ++j){
        float pe = __uint_as_float(ps[j] << 16);      // even l = 2j
        float po = __uint_as_float(ps[j] & HIM);      // odd  l = 2j+1
        float qe = pe * T[k][2*j];
        float qo = po * T[k][2*j+1];
        T[k][2*j]   = qe;
        T[k][2*j+1] = qo;
        a = fmaf(qe, sl[2*j], a);
        a = fmaf(qo, sl[2*j+1], a);
      }
      a = rowsum32(a);
      float dl = __builtin_amdgcn_rcpf((float)NI * a);   // delta_i
      if (k == 24) dl = ok24 ? dl : 0.f;                 // dead rows: no 0*inf
      #pragma unroll
      for (int l = 0; l < 8; ++l){
        T[k][l] *= dl;                                   // T = delta*Q
        cpl[l] += T[k][l];
      }
    }
    #pragma unroll
    for (int l = 0; l < 8; ++l) cp[R][c + 32*l] = cpl[l];  // bank c: conflict-free
    __syncthreads();
    {
      float s = 0.f;
      #pragma unroll
      for (int g = 0; g < 8; ++g) s += cp[g][t];
      sgm[t] = __builtin_amdgcn_rcpf((float)NT * s);       // sigma_j
    }
    __syncthreads();
    #pragma unroll
    for (int l = 0; l < 8; ++l) sl[l] = sgm[c + 32*l];
    #pragma unroll
    for (int k = 0; k < 25; ++k)
      #pragma unroll
      for (int l = 0; l < 8; ++l) T[k][l] *= sl[l];        // T = delta*Q*sigma
  }

  // ---- write T; wd = -sum(C.T) with exact re-read C ----
  float* To = Tout + (size_t)b * NI * NT;
  float acc = 0.f;
  #pragma unroll
  for (int k = 0; k < 25; ++k){
    int i = R + 8*k;
    if ((k < 24) | ok24){
      #pragma unroll
      for (int l = 0; l < 8; ++l){
        To[(size_t)i*NT + c + 32*l] = T[k][l];
        if (WD) acc = fmaf(Cb[(size_t)i*NT + c + 32*l], T[k][l], acc);
      }
    }
  }
  if (WD){
    #pragma unroll
    for (int m = 32; m >= 1; m >>= 1) acc += __shfl_xor(acc, m);
    if ((t & 63) == 0) wp[t >> 6] = acc;
    __syncthreads();
    if (t == 0) distBuf[b] = -(wp[0] + wp[1] + wp[2] + wp[3]);
  }
}

// ---------------- GW final distance + copy gamma to output ----------------
__global__ __launch_bounds__(256) void gwdist_k(const float* __restrict__ Cg, const float* __restrict__ gam,
                                                float* __restrict__ outT, float* __restrict__ gwd){
  int b = blockIdx.x, t = threadIdx.x;
  const float* cb = Cg + (size_t)b*NI*NT;
  const float* gb = gam + (size_t)b*NI*NT;
  float* ob = outT + (size_t)b*NI*NT;
  float a = 0.f;
  for (int i = t; i < NI*NT; i += 256){
    float g = gb[i];
    a = fmaf(cb[i], g, a);
    ob[i] = g;
  }
  #pragma unroll
  for (int m = 32; m >= 1; m >>= 1) a += __shfl_xor(a, m);
  __shared__ float ps[4];
  if ((t & 63) == 0) ps[t>>6] = a;
  __syncthreads();
  if (t == 0) gwd[b] = ps[0]+ps[1]+ps[2]+ps[3];
}

// ---------------- final scalar ----------------
__global__ void fin_k(const float* __restrict__ wd, const float* __restrict__ gwd, float* __restrict__ out){
  int t = threadIdx.x;
  float w = (t < BS) ? wd[t] : 0.f;
  float g = (t < BS) ? gwd[t] : 0.f;
  #pragma unroll
  for (int m = 32; m >= 1; m >>= 1){ w += __shfl_xor(w, m); g += __shfl_xor(g, m); }
  if (t == 0) out[0] = 0.1f * (g / (float)BS) + 0.1f * (w / (float)BS);
}

extern "C" void kernel_launch(void* const* d_in, const int* in_sizes, int n_in,
                              void* d_out, int out_size, void* d_ws, size_t ws_size,
                              hipStream_t stream){
  const float* img  = (const float*)d_in[0];   // (32,196,1024)
  const float* tok  = (const float*)d_in[1];   // (32,256,1024)
  const float* tmsk = (const float*)d_in[2];   // (32,256)
  const int*   tdm  = (const int*)d_in[3];     // (32,256,256)
  const int*   irm  = (const int*)d_in[4];     // (32,196,196)
  float* out = (float*)d_out;                  // [twd, T_wd, T_gwd]

  float* ws = (float*)d_ws;
  size_t off = 0;
  float* cosIT = ws + off; off += (size_t)BS*NI*NT;
  float* Cs    = ws + off; off += (size_t)BS*NI*NI;
  float* Ct    = ws + off; off += (size_t)BS*NT*NT;
  // X region: bf16 hi/lo of img for cosmm; later aliased by gamma/Cgam/G1
  float* Xreg  = ws + off; off += (size_t)BS*NI*DD;           // 6.42M floats
  float* gamma = Xreg;
  float* Cgam  = Xreg + (size_t)BS*NI*NT;
  float* G1    = Xreg + (size_t)2*BS*NI*NT;                   // 4.8M <= 6.42M ok
  unsigned short* Xh = (unsigned short*)Xreg;
  unsigned short* Xl = Xh + (size_t)BS*NI*DD;
  // Y region: bf16 hi/lo of tok; later aliased by GW split buffers
  float* Yreg  = ws + off; off += (size_t)BS*NT*DD;           // 8.39M floats
  unsigned short* Yh = (unsigned short*)Yreg;
  unsigned short* Yl = Yh + (size_t)BS*NT*DD;
  unsigned short* Csh = (unsigned short*)Yreg;                        // 32*196*224
  unsigned short* Csl = Csh + (size_t)BS*NI*224;
  unsigned short* Cth = Csl + (size_t)BS*NI*224;                      // 32*256*256
  unsigned short* Ctl = Cth + (size_t)BS*NT*256;
  unsigned short* gTh = Ctl + (size_t)BS*NT*256;                      // 32*256*224
  unsigned short* gTl = gTh + (size_t)BS*NT*224;
  unsigned short* G1h = gTl + (size_t)BS*NT*224;                      // 32*196*256
  unsigned short* G1l = G1h + (size_t)BS*NI*256;
  float* avec  = ws + off; off += (size_t)BS*NI;
  float* bvec  = ws + off; off += (size_t)BS*NT;
  u32*   mm    = (u32*)(ws + off); off += 8;
  float* wd_b  = ws + off; off += BS;
  float* gwd_b = ws + off; off += BS;

  init_mm_k<<<1, 64, 0, stream>>>(mm);

  // normalize + bf16 hi/lo split
  prep_k<<<dim3(NI,BS), 256, 0, stream>>>(img, nullptr, Xh, Xl, NI);
  prep_k<<<dim3(NT,BS), 256, 0, stream>>>(tok, tmsk,    Yh, Yl, NT);

  // cosine cost matrices via MFMA (Markidis split)
  cosmm_k<<<dim3(4, BS), 256, 0, stream>>>(Xh, Xl, Yh, Yl, cosIT, NI, NT, 2);
  cosmm_k<<<dim3(4, BS), 256, 0, stream>>>(Xh, Xl, Xh, Xl, Cs,    NI, NI, 2);
  cosmm_k<<<dim3(4, BS), 256, 0, stream>>>(Yh, Yl, Yh, Yl, Ct,    NT, NT, 2);

  // global min/max then threshold-relu (+mask for Cs/Ct)
  minmax_k<<<512, 256, 0, stream>>>(cosIT, (size_t)BS*NI*NT, mm+0);
  minmax_k<<<512, 256, 0, stream>>>(Cs,    (size_t)BS*NI*NI, mm+2);
  minmax_k<<<512, 256, 0, stream>>>(Ct,    (size_t)BS*NT*NT, mm+4);
  thresh_k<<<1024, 256, 0, stream>>>(cosIT, nullptr, (size_t)BS*NI*NT, mm+0);
  thresh_k<<<1024, 256, 0, stream>>>(Cs,    irm,     (size_t)BS*NI*NI, mm+2);
  thresh_k<<<1024, 256, 0, stream>>>(Ct,    tdm,     (size_t)BS*NT*NT, mm+4);

  // Cst components
  rowmeansq_k<<<dim3(NI,BS), 64, 0, stream>>>(Cs, avec, NI, NI);
  rowmeansq_k<<<dim3(NT,BS), 64, 0, stream>>>(Ct, bvec, NT, NT);

  // one-time bf16 splits of thresholded Cs (K-pad 224) and Ct (K=256)
  split_k<<<dim3(NI,BS), 256, 0, stream>>>(Cs, Csh, Csl, NI, 224);
  split_k<<<dim3(NT,BS), 256, 0, stream>>>(Ct, Cth, Ctl, NT, 256);

  // wd-IPOT (writes T_wd and wd)
  ipotr3_k<true><<<BS, 256, 0, stream>>>(cosIT, out + 1, wd_b);

  // GW loop
  fill_k<<<512, 256, 0, stream>>>(gamma, (size_t)BS*NI*NT, 1.0f/((float)NI*(float)NT));
  for (int itn = 0; itn < 6; ++itn){
    splitT_k<<<dim3(8, 7, BS), 256, 0, stream>>>(gamma, gTh, gTl);
    mmnt_k<0><<<dim3(16, BS), 256, 0, stream>>>(Csh, Csl, gTh, gTl, G1, NI, NT, 224, 4, nullptr, nullptr);
    split_k<<<dim3(NI,BS), 256, 0, stream>>>(G1, G1h, G1l, NT, 256);
    mmnt_k<2><<<dim3(16, BS), 256, 0, stream>>>(G1h, G1l, Cth, Ctl, Cgam, NI, NT, 256, 4, avec, bvec);
    if (itn < 5)
      ipotr3_k<false><<<BS, 256, 0, stream>>>(Cgam, gamma, nullptr);
  }

  gwdist_k<<<BS, 256, 0, stream>>>(Cgam, gamma, out + 1 + (size_t)BS*NI*NT, gwd_b);
  fin_k<<<1, 64, 0, stream>>>(wd_b, gwd_b, out);
}

// Round 9
// 872.240 us; speedup vs baseline: 1.3280x; 1.3280x over previous
//
#include <hip/hip_runtime.h>
#include <math.h>

#define BS 32
#define NI 196
#define NT 256
#define DD 1024

typedef unsigned int u32;
typedef __attribute__((ext_vector_type(8))) short bf16x8;
typedef __attribute__((ext_vector_type(4))) float f32x4;

__device__ __forceinline__ u32 fenc(float f){ u32 u = __float_as_uint(f); return (u & 0x80000000u) ? ~u : (u | 0x80000000u); }
__device__ __forceinline__ float fdec(u32 u){ return __uint_as_float((u & 0x80000000u) ? (u & 0x7fffffffu) : ~u); }

// bf16 helpers (manual RNE)
__device__ __forceinline__ unsigned short f2bf(float f){
  u32 u = __float_as_uint(f);
  u32 r = (u + 0x7FFFu + ((u >> 16) & 1u)) >> 16;
  return (unsigned short)r;
}
__device__ __forceinline__ float bf2f(unsigned short h){ return __uint_as_float((u32)h << 16); }

template<int CTRL>
__device__ __forceinline__ float dppadd(float x){
  int y = __builtin_amdgcn_update_dpp(0, __float_as_int(x), CTRL, 0xF, 0xF, false);
  return x + __int_as_float(y);
}
// sum over each 32-lane half of the wave
__device__ __forceinline__ float rowsum32(float x){
  x = dppadd<0xB1>(x);    // quad_perm xor1
  x = dppadd<0x4E>(x);    // quad_perm xor2
  x = dppadd<0x141>(x);   // row_half_mirror (pairs within 8)
  x = dppadd<0x128>(x);   // row_ror:8 (pairs within 16)
  x += __shfl_xor(x, 16);
  return x;
}

// ---------------- init ----------------
__global__ void init_mm_k(u32* mm){
  int t = threadIdx.x;
  if (t < 3){ mm[2*t] = 0xFFFFFFFFu; mm[2*t+1] = 0u; }
}

// ---------------- prep: normalize rows, split to bf16 hi/lo ----------------
__global__ __launch_bounds__(256) void prep_k(const float* __restrict__ feat,
                                              const float* __restrict__ mask,
                                              unsigned short* __restrict__ hi,
                                              unsigned short* __restrict__ lo, int R){
  int b = blockIdx.y, r = blockIdx.x, t = threadIdx.x;
  size_t rowoff = ((size_t)b*R + r)*DD;
  float4 v = ((const float4*)(feat + rowoff))[t];
  float s = v.x*v.x + v.y*v.y + v.z*v.z + v.w*v.w;
  #pragma unroll
  for (int m = 32; m >= 1; m >>= 1) s += __shfl_xor(s, m);
  __shared__ float ps[4];
  if ((t & 63) == 0) ps[t >> 6] = s;
  __syncthreads();
  float tot = ps[0] + ps[1] + ps[2] + ps[3];
  float mv = mask ? mask[b*R + r] : 1.0f;
  float sc = mv / (mv * sqrtf(tot) + 1e-12f);
  float x[4] = {v.x*sc, v.y*sc, v.z*sc, v.w*sc};
  unsigned short h[4], l[4];
  #pragma unroll
  for (int i = 0; i < 4; ++i){
    h[i] = f2bf(x[i]);
    l[i] = f2bf(x[i] - bf2f(h[i]));
  }
  *(ushort4*)(hi + rowoff + t*4) = make_ushort4(h[0],h[1],h[2],h[3]);
  *(ushort4*)(lo + rowoff + t*4) = make_ushort4(l[0],l[1],l[2],l[3]);
}

// ---------------- MFMA cos GEMM: C = 1 - Xn . Yn^T (128x128 tile) ----------------
__global__ __launch_bounds__(256) void cosmm_k(const unsigned short* __restrict__ Xh,
                                               const unsigned short* __restrict__ Xl,
                                               const unsigned short* __restrict__ Yh,
                                               const unsigned short* __restrict__ Yl,
                                               float* __restrict__ C, int M, int N, int nTN){
  __shared__ unsigned short Ah[128*40], Al[128*40], Bh[128*40], Bl[128*40];
  int b = blockIdx.y;
  int tm = (blockIdx.x / nTN) * 128, tn = (blockIdx.x % nTN) * 128;
  int t = threadIdx.x, lane = t & 63, w = t >> 6;
  int wm = (w >> 1) * 64, wn = (w & 1) * 64;
  const unsigned short* Xhb = Xh + (size_t)b*M*DD;
  const unsigned short* Xlb = Xl + (size_t)b*M*DD;
  const unsigned short* Yhb = Yh + (size_t)b*N*DD;
  const unsigned short* Ylb = Yl + (size_t)b*N*DD;
  f32x4 acc[4][4];
  #pragma unroll
  for (int m = 0; m < 4; ++m)
    #pragma unroll
    for (int n = 0; n < 4; ++n) acc[m][n] = (f32x4){0.f,0.f,0.f,0.f};

  int sr0 = t >> 2, sc0 = (t & 3) * 8;
  int gr0 = min(tm + sr0, M-1),      gr1 = min(tm + sr0 + 64, M-1);
  int gc0 = min(tn + sr0, N-1),      gc1 = min(tn + sr0 + 64, N-1);
  const unsigned short* pa0 = Xhb + (size_t)gr0*DD + sc0;
  const unsigned short* pa1 = Xhb + (size_t)gr1*DD + sc0;
  const unsigned short* pa2 = Xlb + (size_t)gr0*DD + sc0;
  const unsigned short* pa3 = Xlb + (size_t)gr1*DD + sc0;
  const unsigned short* pb0 = Yhb + (size_t)gc0*DD + sc0;
  const unsigned short* pb1 = Yhb + (size_t)gc1*DD + sc0;
  const unsigned short* pb2 = Ylb + (size_t)gc0*DD + sc0;
  const unsigned short* pb3 = Ylb + (size_t)gc1*DD + sc0;
  int fr = lane & 15, fk = (lane >> 4) * 8;

  for (int k0 = 0; k0 < DD; k0 += 32){
    float4 a0 = *(const float4*)(pa0 + k0);
    float4 a1 = *(const float4*)(pa1 + k0);
    float4 a2 = *(const float4*)(pa2 + k0);
    float4 a3 = *(const float4*)(pa3 + k0);
    float4 b0 = *(const float4*)(pb0 + k0);
    float4 b1 = *(const float4*)(pb1 + k0);
    float4 b2 = *(const float4*)(pb2 + k0);
    float4 b3 = *(const float4*)(pb3 + k0);
    __syncthreads();
    *(float4*)&Ah[sr0*40 + sc0]      = a0;
    *(float4*)&Ah[(sr0+64)*40 + sc0] = a1;
    *(float4*)&Al[sr0*40 + sc0]      = a2;
    *(float4*)&Al[(sr0+64)*40 + sc0] = a3;
    *(float4*)&Bh[sr0*40 + sc0]      = b0;
    *(float4*)&Bh[(sr0+64)*40 + sc0] = b1;
    *(float4*)&Bl[sr0*40 + sc0]      = b2;
    *(float4*)&Bl[(sr0+64)*40 + sc0] = b3;
    __syncthreads();
    bf16x8 ah[4], al[4], bh[4], bl[4];
    #pragma unroll
    for (int m = 0; m < 4; ++m){
      int r = wm + m*16 + fr;
      ah[m] = *(bf16x8*)&Ah[r*40 + fk];
      al[m] = *(bf16x8*)&Al[r*40 + fk];
    }
    #pragma unroll
    for (int n = 0; n < 4; ++n){
      int r = wn + n*16 + fr;
      bh[n] = *(bf16x8*)&Bh[r*40 + fk];
      bl[n] = *(bf16x8*)&Bl[r*40 + fk];
    }
    #pragma unroll
    for (int m = 0; m < 4; ++m)
      #pragma unroll
      for (int n = 0; n < 4; ++n){
        acc[m][n] = __builtin_amdgcn_mfma_f32_16x16x32_bf16(ah[m], bh[n], acc[m][n], 0,0,0);
        acc[m][n] = __builtin_amdgcn_mfma_f32_16x16x32_bf16(ah[m], bl[n], acc[m][n], 0,0,0);
        acc[m][n] = __builtin_amdgcn_mfma_f32_16x16x32_bf16(al[m], bh[n], acc[m][n], 0,0,0);
      }
  }
  float* Cb = C + (size_t)b*M*N;
  #pragma unroll
  for (int m = 0; m < 4; ++m){
    int row0 = tm + wm + m*16 + ((lane >> 4) << 2);
    #pragma unroll
    for (int n = 0; n < 4; ++n){
      int col = tn + wn + n*16 + (lane & 15);
      if (col < N){
        #pragma unroll
        for (int r = 0; r < 4; ++r){
          int row = row0 + r;
          if (row < M) Cb[(size_t)row*N + col] = 1.0f - acc[m][n][r];
        }
      }
    }
  }
}

// ---------------- MFMA NT GEMM on pre-split bf16 operands (64x64 tile) ----------------
template<int EPI>
__global__ __launch_bounds__(256) void mmnt_k(const unsigned short* __restrict__ Ah,
                                              const unsigned short* __restrict__ Al,
                                              const unsigned short* __restrict__ Bh,
                                              const unsigned short* __restrict__ Bl,
                                              float* __restrict__ C,
                                              int M, int N, int Kp, int nTN,
                                              const float* __restrict__ av,
                                              const float* __restrict__ bv){
  __shared__ unsigned short As_h[64*40], As_l[64*40], Bs_h[64*40], Bs_l[64*40];
  int b = blockIdx.y;
  int tm = (blockIdx.x / nTN) * 64, tn = (blockIdx.x % nTN) * 64;
  int t = threadIdx.x, lane = t & 63, w = t >> 6;
  int wm = (w >> 1) * 32, wn = (w & 1) * 32;
  const unsigned short* Ahb = Ah + (size_t)b*M*Kp;
  const unsigned short* Alb = Al + (size_t)b*M*Kp;
  const unsigned short* Bhb = Bh + (size_t)b*N*Kp;
  const unsigned short* Blb = Bl + (size_t)b*N*Kp;
  f32x4 acc[2][2];
  #pragma unroll
  for (int m = 0; m < 2; ++m)
    #pragma unroll
    for (int n = 0; n < 2; ++n) acc[m][n] = (f32x4){0.f,0.f,0.f,0.f};

  int srow = t >> 2, sch = (t & 3) * 8;
  int ga = min(tm + srow, M-1), gbn = min(tn + srow, N-1);
  const unsigned short* pah = Ahb + (size_t)ga*Kp + sch;
  const unsigned short* pal = Alb + (size_t)ga*Kp + sch;
  const unsigned short* pbh = Bhb + (size_t)gbn*Kp + sch;
  const unsigned short* pbl = Blb + (size_t)gbn*Kp + sch;
  int fr = lane & 15, fk = (lane >> 4) * 8;

  for (int k0 = 0; k0 < Kp; k0 += 32){
    float4 vah = *(const float4*)(pah + k0);
    float4 val = *(const float4*)(pal + k0);
    float4 vbh = *(const float4*)(pbh + k0);
    float4 vbl = *(const float4*)(pbl + k0);
    __syncthreads();
    *(float4*)&As_h[srow*40 + sch] = vah;
    *(float4*)&As_l[srow*40 + sch] = val;
    *(float4*)&Bs_h[srow*40 + sch] = vbh;
    *(float4*)&Bs_l[srow*40 + sch] = vbl;
    __syncthreads();
    bf16x8 fah[2], fal[2], fbh[2], fbl[2];
    #pragma unroll
    for (int m = 0; m < 2; ++m){
      int r = wm + m*16 + fr;
      fah[m] = *(bf16x8*)&As_h[r*40 + fk];
      fal[m] = *(bf16x8*)&As_l[r*40 + fk];
    }
    #pragma unroll
    for (int n = 0; n < 2; ++n){
      int r = wn + n*16 + fr;
      fbh[n] = *(bf16x8*)&Bs_h[r*40 + fk];
      fbl[n] = *(bf16x8*)&Bs_l[r*40 + fk];
    }
    #pragma unroll
    for (int m = 0; m < 2; ++m)
      #pragma unroll
      for (int n = 0; n < 2; ++n){
        acc[m][n] = __builtin_amdgcn_mfma_f32_16x16x32_bf16(fah[m], fbh[n], acc[m][n], 0,0,0);
        acc[m][n] = __builtin_amdgcn_mfma_f32_16x16x32_bf16(fah[m], fbl[n], acc[m][n], 0,0,0);
        acc[m][n] = __builtin_amdgcn_mfma_f32_16x16x32_bf16(fal[m], fbh[n], acc[m][n], 0,0,0);
      }
  }
  float* Cb = C + (size_t)b*M*N;
  #pragma unroll
  for (int m = 0; m < 2; ++m){
    int row0 = tm + wm + m*16 + ((lane >> 4) << 2);
    #pragma unroll
    for (int n = 0; n < 2; ++n){
      int col = tn + wn + n*16 + (lane & 15);
      #pragma unroll
      for (int r = 0; r < 4; ++r){
        int row = row0 + r;
        if (row < M){
          float x = acc[m][n][r];
          if (EPI == 2) x = av[b*M + row] + bv[b*N + col] - 2.0f*x;
          Cb[(size_t)row*N + col] = x;
        }
      }
    }
  }
}

// ---------------- plain bf16 hi/lo split with K zero-padding ----------------
__global__ __launch_bounds__(256) void split_k(const float* __restrict__ src,
                                               unsigned short* __restrict__ dsth,
                                               unsigned short* __restrict__ dstl,
                                               int Cin, int Kp){
  int r = blockIdx.x, b = blockIdx.y, j = threadIdx.x, R = gridDim.x;
  if (j >= Kp) return;
  float v = (j < Cin) ? src[((size_t)b*R + r)*Cin + j] : 0.f;
  unsigned short h = f2bf(v);
  unsigned short l = f2bf(v - bf2f(h));
  size_t o = ((size_t)b*R + r)*Kp + j;
  dsth[o] = h; dstl[o] = l;
}

// ---------------- transpose + split: gamma [196][256] -> gT h/l [256][224] ----------------
__global__ __launch_bounds__(256) void splitT_k(const float* __restrict__ g,
                                                unsigned short* __restrict__ th,
                                                unsigned short* __restrict__ tl){
  __shared__ float tile[32][33];
  int j0 = blockIdx.x * 32, k0 = blockIdx.y * 32, b = blockIdx.z;
  int t = threadIdx.x;
  const float* gb = g + (size_t)b*NI*NT;
  {
    int a = t >> 3, ch = t & 7;
    int k = k0 + a;
    float4 v = make_float4(0.f,0.f,0.f,0.f);
    if (k < NI) v = *(const float4*)(gb + (size_t)k*NT + j0 + ch*4);
    tile[a][ch*4+0] = v.x; tile[a][ch*4+1] = v.y; tile[a][ch*4+2] = v.z; tile[a][ch*4+3] = v.w;
  }
  __syncthreads();
  {
    int jloc = t >> 3, ch = t & 7;
    int j = j0 + jloc;
    unsigned short h[4], l[4];
    #pragma unroll
    for (int r = 0; r < 4; ++r){
      float v = tile[ch*4 + r][jloc];
      h[r] = f2bf(v);
      l[r] = f2bf(v - bf2f(h[r]));
    }
    size_t o = ((size_t)b*NT + j)*224 + k0 + ch*4;
    *(ushort4*)(th + o) = make_ushort4(h[0],h[1],h[2],h[3]);
    *(ushort4*)(tl + o) = make_ushort4(l[0],l[1],l[2],l[3]);
  }
}

// ---------------- global min/max ----------------
__global__ __launch_bounds__(256) void minmax_k(const float* __restrict__ X, size_t cnt, u32* __restrict__ mm){
  size_t stride = (size_t)gridDim.x * blockDim.x;
  float mn = 3.402823466e38f, mx = -3.402823466e38f;
  for (size_t i = (size_t)blockIdx.x*blockDim.x + threadIdx.x; i < cnt; i += stride){
    float v = X[i]; mn = fminf(mn, v); mx = fmaxf(mx, v);
  }
  #pragma unroll
  for (int m = 32; m >= 1; m >>= 1){ mn = fminf(mn, __shfl_xor(mn, m)); mx = fmaxf(mx, __shfl_xor(mx, m)); }
  __shared__ float smn[4], smx[4];
  int t = threadIdx.x;
  if ((t & 63) == 0){ smn[t>>6] = mn; smx[t>>6] = mx; }
  __syncthreads();
  if (t == 0){
    mn = fminf(fminf(smn[0], smn[1]), fminf(smn[2], smn[3]));
    mx = fmaxf(fmaxf(smx[0], smx[1]), fmaxf(smx[2], smx[3]));
    atomicMin(&mm[0], fenc(mn));
    atomicMax(&mm[1], fenc(mx));
  }
}

// ---------------- threshold-relu (+ optional {0,1}->{1e-5,1} mask) ----------------
__global__ __launch_bounds__(256) void thresh_k(float* __restrict__ X, const int* __restrict__ msk,
                                                size_t cnt, const u32* __restrict__ mm){
  float mn = fdec(mm[0]), mx = fdec(mm[1]);
  float thr = mn + 0.1f * (mx - mn);
  size_t stride = (size_t)gridDim.x * blockDim.x;
  for (size_t i = (size_t)blockIdx.x*blockDim.x + threadIdx.x; i < cnt; i += stride){
    float v = X[i] - thr;
    v = v > 0.f ? v : 0.f;
    if (msk) v *= (msk[i] == 1 ? 1.0f : 1e-5f);
    X[i] = v;
  }
}

// ---------------- row stats: mean of squares + plain sum ----------------
__global__ __launch_bounds__(64) void rowstat_k(const float* __restrict__ X, float* __restrict__ outms,
                                                float* __restrict__ outsum, int R, int Cc){
  int b = blockIdx.y, r = blockIdx.x, t = threadIdx.x;
  const float* row = X + ((size_t)b*R + r) * Cc;
  float s1 = 0.f, s2 = 0.f;
  for (int j = t; j < Cc; j += 64){ float v = row[j]; s1 += v; s2 = fmaf(v, v, s2); }
  #pragma unroll
  for (int m = 32; m >= 1; m >>= 1){ s1 += __shfl_xor(s1, m); s2 += __shfl_xor(s2, m); }
  if (t == 0){ outms[b*R + r] = s2 / (float)Cc; outsum[b*R + r] = s1; }
}

// ---------------- Cgam for uniform gamma0 (closed form, no GEMMs) ----------------
// Cgam0[i][j] = avec[i] + bvec[j] - (2/(n*m)) * rowsum(Cs)[i] * rowsum(Ct)[j]
__global__ __launch_bounds__(256) void cgam0_k(const float* __restrict__ av, const float* __restrict__ bv,
                                               const float* __restrict__ rsA, const float* __restrict__ rsB,
                                               float* __restrict__ Cg){
  int b = blockIdx.y, i = blockIdx.x, j = threadIdx.x;
  const float c2 = 2.0f / ((float)NI * (float)NT);
  Cg[((size_t)b*NI + i)*NT + j] = av[b*NI + i] + bv[b*NT + j] - c2 * rsA[b*NI + i] * rsB[b*NT + j];
}

// ---------------- IPOT v5: 1024 thr (16 waves), T fp32 regs, P bf16 LDS ----------------
// One block per matrix; grid 32 (one set) or 64 (A-set blocks 0..31 + B-set 32..63,
// run CONCURRENTLY on different CUs - used to overlap wd-ipot with the first GW ipot).
// thread: c = t&31 (cols j = c+32l, l<8), R = t>>5 in 0..31 (rows i = R+32k, k<7;
// k==6 valid iff R<4 -> 196 rows).
// r8 lesson: spill fixed (VGPR=256, conflicts 0) but 256 thr = 1 wave/SIMD left the
// kernel latency-exposed at 4.8x the VALU bound. 1024 thr = 4 waves/SIMD hides it.
// Per-thread: T[7][8]=56 fp32 + ~45 working ~= 105 VGPR < 128 cap -> no spill.
// LDS: P 112 KB + cp 32 KB + sgm 1 KB = 148.5 KB (fits 160; >64KB static OK per r8).
__global__ __launch_bounds__(1024, 1) void ipotr4_k(const float* __restrict__ CA,
                                                    float* __restrict__ TA,
                                                    const float* __restrict__ CB,
                                                    float* __restrict__ TB,
                                                    float* __restrict__ distBuf){
  __shared__ u32 Ppk[32*7*32*4];      // [R][k][c][pair] = 114,688 B
  __shared__ float cp[32][NT];        // 32 KB
  __shared__ float sgm[NT];
  __shared__ float wp[16];
  const u32 HIM = 0xFFFF0000u;
  int g = blockIdx.x, t = threadIdx.x;
  int b = g & 31;
  bool second = (g >= 32);
  const float* Cb = (second ? CB : CA) + (size_t)b * NI * NT;
  float* To = (second ? TB : TA) + (size_t)b * NI * NT;
  bool doWD = (!second) && (distBuf != nullptr);
  int c = t & 31, R = t >> 5;
  bool ok6 = (R < 4);                  // row 192+R valid iff R<4
  u32* myP = &Ppk[((R*7)*32 + c)*4];

  float T[7][8];
  // ---- load C -> P=exp(-2C) -> pack bf16 pairs to LDS ----
  #pragma unroll
  for (int k = 0; k < 7; ++k){
    int i = R + 32*k;
    bool ok = (k < 6) | ok6;
    float cv[8];
    #pragma unroll
    for (int l = 0; l < 8; ++l)
      cv[l] = ok ? Cb[(size_t)i*NT + c + 32*l] : 0.f;
    u32 pk[4];
    #pragma unroll
    for (int j = 0; j < 4; ++j){
      float p0 = ok ? __expf(-2.0f*cv[2*j])   : 0.f;
      float p1 = ok ? __expf(-2.0f*cv[2*j+1]) : 0.f;
      pk[j] = (u32)f2bf(p0) | ((u32)f2bf(p1) << 16);
    }
    *(uint4*)(myP + k*128) = make_uint4(pk[0], pk[1], pk[2], pk[3]);
    #pragma unroll
    for (int l = 0; l < 8; ++l) T[k][l] = ok ? 1.f : 0.f;
  }

  float sl[8];
  #pragma unroll
  for (int l = 0; l < 8; ++l) sl[l] = 1.0f / (float)NT;   // sigma carry (init 1/m)

  #pragma unroll 1
  for (int it = 0; it < 20; ++it){
    float cpl[8];
    #pragma unroll
    for (int l = 0; l < 8; ++l) cpl[l] = 0.f;
    #pragma unroll
    for (int k = 0; k < 7; ++k){
      uint4 pq = *(const uint4*)(myP + k*128);
      u32 ps[4] = {pq.x, pq.y, pq.z, pq.w};
      float a = 0.f;
      #pragma unroll
      for (int j = 0; j < 4; ++j){
        float pe = __uint_as_float(ps[j] << 16);      // even l = 2j
        float po = __uint_as_float(ps[j] & HIM);      // odd  l = 2j+1
        float qe = pe * T[k][2*j];
        float qo = po * T[k][2*j+1];
        T[k][2*j]   = qe;
        T[k][2*j+1] = qo;
        a = fmaf(qe, sl[2*j], a);
        a = fmaf(qo, sl[2*j+1], a);
      }
      a = rowsum32(a);
      float dl = __builtin_amdgcn_rcpf((float)NI * a);   // delta_i
      if (k == 6) dl = ok6 ? dl : 0.f;                   // dead rows: no 0*inf
      #pragma unroll
      for (int l = 0; l < 8; ++l){
        T[k][l] *= dl;                                   // T = delta*Q
        cpl[l] += T[k][l];
      }
    }
    #pragma unroll
    for (int l = 0; l < 8; ++l) cp[R][c + 32*l] = cpl[l];  // 2-way alias: free
    __syncthreads();
    if (t < NT){
      float s0 = 0.f, s1 = 0.f, s2 = 0.f, s3 = 0.f;
      #pragma unroll
      for (int q = 0; q < 32; q += 4){
        s0 += cp[q][t]; s1 += cp[q+1][t]; s2 += cp[q+2][t]; s3 += cp[q+3][t];
      }
      sgm[t] = __builtin_amdgcn_rcpf((float)NT * ((s0+s1)+(s2+s3)));   // sigma_j
    }
    __syncthreads();
    #pragma unroll
    for (int l = 0; l < 8; ++l) sl[l] = sgm[c + 32*l];
    #pragma unroll
    for (int k = 0; k < 7; ++k)
      #pragma unroll
      for (int l = 0; l < 8; ++l) T[k][l] *= sl[l];        // T = delta*Q*sigma
  }

  // ---- write T; wd = -sum(C.T) with exact re-read C ----
  float acc = 0.f;
  #pragma unroll
  for (int k = 0; k < 7; ++k){
    int i = R + 32*k;
    if ((k < 6) | ok6){
      #pragma unroll
      for (int l = 0; l < 8; ++l){
        To[(size_t)i*NT + c + 32*l] = T[k][l];
        if (doWD) acc = fmaf(Cb[(size_t)i*NT + c + 32*l], T[k][l], acc);
      }
    }
  }
  if (doWD){
    #pragma unroll
    for (int m = 32; m >= 1; m >>= 1) acc += __shfl_xor(acc, m);
    if ((t & 63) == 0) wp[t >> 6] = acc;
    __syncthreads();
    if (t == 0){
      float s = 0.f;
      #pragma unroll
      for (int q = 0; q < 16; ++q) s += wp[q];
      distBuf[b] = -s;
    }
  }
}

// ---------------- GW final distance + copy gamma to output ----------------
__global__ __launch_bounds__(256) void gwdist_k(const float* __restrict__ Cg, const float* __restrict__ gam,
                                                float* __restrict__ outT, float* __restrict__ gwd){
  int b = blockIdx.x, t = threadIdx.x;
  const float* cb = Cg + (size_t)b*NI*NT;
  const float* gb = gam + (size_t)b*NI*NT;
  float* ob = outT + (size_t)b*NI*NT;
  float a = 0.f;
  for (int i = t; i < NI*NT; i += 256){
    float g = gb[i];
    a = fmaf(cb[i], g, a);
    ob[i] = g;
  }
  #pragma unroll
  for (int m = 32; m >= 1; m >>= 1) a += __shfl_xor(a, m);
  __shared__ float ps[4];
  if ((t & 63) == 0) ps[t>>6] = a;
  __syncthreads();
  if (t == 0) gwd[b] = ps[0]+ps[1]+ps[2]+ps[3];
}

// ---------------- final scalar ----------------
__global__ void fin_k(const float* __restrict__ wd, const float* __restrict__ gwd, float* __restrict__ out){
  int t = threadIdx.x;
  float w = (t < BS) ? wd[t] : 0.f;
  float g = (t < BS) ? gwd[t] : 0.f;
  #pragma unroll
  for (int m = 32; m >= 1; m >>= 1){ w += __shfl_xor(w, m); g += __shfl_xor(g, m); }
  if (t == 0) out[0] = 0.1f * (g / (float)BS) + 0.1f * (w / (float)BS);
}

extern "C" void kernel_launch(void* const* d_in, const int* in_sizes, int n_in,
                              void* d_out, int out_size, void* d_ws, size_t ws_size,
                              hipStream_t stream){
  const float* img  = (const float*)d_in[0];   // (32,196,1024)
  const float* tok  = (const float*)d_in[1];   // (32,256,1024)
  const float* tmsk = (const float*)d_in[2];   // (32,256)
  const int*   tdm  = (const int*)d_in[3];     // (32,256,256)
  const int*   irm  = (const int*)d_in[4];     // (32,196,196)
  float* out = (float*)d_out;                  // [twd, T_wd, T_gwd]

  float* ws = (float*)d_ws;
  size_t off = 0;
  float* cosIT = ws + off; off += (size_t)BS*NI*NT;
  float* Cs    = ws + off; off += (size_t)BS*NI*NI;
  float* Ct    = ws + off; off += (size_t)BS*NT*NT;
  // X region: bf16 hi/lo of img for cosmm; later aliased by gamma/Cgam/G1
  float* Xreg  = ws + off; off += (size_t)BS*NI*DD;           // 6.42M floats
  float* gamma = Xreg;
  float* Cgam  = Xreg + (size_t)BS*NI*NT;
  float* G1    = Xreg + (size_t)2*BS*NI*NT;                   // 4.8M <= 6.42M ok
  unsigned short* Xh = (unsigned short*)Xreg;
  unsigned short* Xl = Xh + (size_t)BS*NI*DD;
  // Y region: bf16 hi/lo of tok; later aliased by GW split buffers
  float* Yreg  = ws + off; off += (size_t)BS*NT*DD;           // 8.39M floats
  unsigned short* Yh = (unsigned short*)Yreg;
  unsigned short* Yl = Yh + (size_t)BS*NT*DD;
  unsigned short* Csh = (unsigned short*)Yreg;                        // 32*196*224
  unsigned short* Csl = Csh + (size_t)BS*NI*224;
  unsigned short* Cth = Csl + (size_t)BS*NI*224;                      // 32*256*256
  unsigned short* Ctl = Cth + (size_t)BS*NT*256;
  unsigned short* gTh = Ctl + (size_t)BS*NT*256;                      // 32*256*224
  unsigned short* gTl = gTh + (size_t)BS*NT*224;
  unsigned short* G1h = gTl + (size_t)BS*NT*224;                      // 32*196*256
  unsigned short* G1l = G1h + (size_t)BS*NI*256;
  float* avec  = ws + off; off += (size_t)BS*NI;
  float* bvec  = ws + off; off += (size_t)BS*NT;
  float* rsCs  = ws + off; off += (size_t)BS*NI;
  float* rsCt  = ws + off; off += (size_t)BS*NT;
  u32*   mm    = (u32*)(ws + off); off += 8;
  float* wd_b  = ws + off; off += BS;
  float* gwd_b = ws + off; off += BS;

  init_mm_k<<<1, 64, 0, stream>>>(mm);

  // normalize + bf16 hi/lo split
  prep_k<<<dim3(NI,BS), 256, 0, stream>>>(img, nullptr, Xh, Xl, NI);
  prep_k<<<dim3(NT,BS), 256, 0, stream>>>(tok, tmsk,    Yh, Yl, NT);

  // cosine cost matrices via MFMA (Markidis split)
  cosmm_k<<<dim3(4, BS), 256, 0, stream>>>(Xh, Xl, Yh, Yl, cosIT, NI, NT, 2);
  cosmm_k<<<dim3(4, BS), 256, 0, stream>>>(Xh, Xl, Xh, Xl, Cs,    NI, NI, 2);
  cosmm_k<<<dim3(4, BS), 256, 0, stream>>>(Yh, Yl, Yh, Yl, Ct,    NT, NT, 2);

  // global min/max then threshold-relu (+mask for Cs/Ct)
  minmax_k<<<512, 256, 0, stream>>>(cosIT, (size_t)BS*NI*NT, mm+0);
  minmax_k<<<512, 256, 0, stream>>>(Cs,    (size_t)BS*NI*NI, mm+2);
  minmax_k<<<512, 256, 0, stream>>>(Ct,    (size_t)BS*NT*NT, mm+4);
  thresh_k<<<1024, 256, 0, stream>>>(cosIT, nullptr, (size_t)BS*NI*NT, mm+0);
  thresh_k<<<1024, 256, 0, stream>>>(Cs,    irm,     (size_t)BS*NI*NI, mm+2);
  thresh_k<<<1024, 256, 0, stream>>>(Ct,    tdm,     (size_t)BS*NT*NT, mm+4);

  // Cst components + rowsums (for the closed-form Cgam0)
  rowstat_k<<<dim3(NI,BS), 64, 0, stream>>>(Cs, avec, rsCs, NI, NI);
  rowstat_k<<<dim3(NT,BS), 64, 0, stream>>>(Ct, bvec, rsCt, NT, NT);

  // one-time bf16 splits of thresholded Cs (K-pad 224) and Ct (K=256)
  split_k<<<dim3(NI,BS), 256, 0, stream>>>(Cs, Csh, Csl, NI, 224);
  split_k<<<dim3(NT,BS), 256, 0, stream>>>(Ct, Cth, Ctl, NT, 256);

  // Cgam for uniform gamma0: closed form, no GEMMs
  cgam0_k<<<dim3(NI,BS), 256, 0, stream>>>(avec, bvec, rsCs, rsCt, Cgam);

  // wd-ipot (blocks 0..31, writes T_wd + wd) CONCURRENT with first GW ipot
  // (blocks 32..63, Cgam0 -> gamma)
  ipotr4_k<<<64, 1024, 0, stream>>>(cosIT, out + 1, Cgam, gamma, wd_b);

  // GW loop: 5 remaining C_gamma computations; ipot after all but the last
  for (int itn = 1; itn < 6; ++itn){
    splitT_k<<<dim3(8, 7, BS), 256, 0, stream>>>(gamma, gTh, gTl);
    mmnt_k<0><<<dim3(16, BS), 256, 0, stream>>>(Csh, Csl, gTh, gTl, G1, NI, NT, 224, 4, nullptr, nullptr);
    split_k<<<dim3(NI,BS), 256, 0, stream>>>(G1, G1h, G1l, NT, 256);
    mmnt_k<2><<<dim3(16, BS), 256, 0, stream>>>(G1h, G1l, Cth, Ctl, Cgam, NI, NT, 256, 4, avec, bvec);
    if (itn < 5)
      ipotr4_k<<<32, 1024, 0, stream>>>(Cgam, gamma, nullptr, nullptr, nullptr);
  }

  gwdist_k<<<BS, 256, 0, stream>>>(Cgam, gamma, out + 1 + (size_t)BS*NI*NT, gwd_b);
  fin_k<<<1, 64, 0, stream>>>(wd_b, gwd_b, out);
}